// Round 7
// baseline (287.879 us; speedup 1.0000x reference)
//
#include <hip/hip_runtime.h>
#include <hip/hip_bf16.h>

// Dense FFN: out = relu(x @ w1 + b1) @ w2 + b2
// x  [8192,1024] f32, w1 [1024,4096] f32, b1 [4096] f32,
// w2 [4096,1024] f32, b2 [1024] f32, out [8192,1024] f32.
// R7: GEMM structure reverts to R2 (the measured best: single-buffer BK=64,
// 2-barrier loop, XOR chunk swizzle, 0 conflicts, ~800 TF = the m97-family
// plateau).  The win target is the ~80us of non-GEMM time: the x-cast
// dispatch is eliminated (GEMM1 stages A straight from f32 with register
// prefetch + cvt + swizzled ds_write_b128 -- R5's staging, measured 0
// conflicts), and prep shrinks to weight transposes only (2048 blocks).

typedef __bf16 bf16;
typedef __bf16 bf16x8 __attribute__((ext_vector_type(8)));
typedef float  f32x4  __attribute__((ext_vector_type(4)));

#define BM 128
#define BN 128
#define BK 64

__device__ __forceinline__ void gload_lds16(const bf16* g, bf16* l) {
    __builtin_amdgcn_global_load_lds(
        (const __attribute__((address_space(1))) unsigned int*)g,
        (__attribute__((address_space(3))) unsigned int*)l,
        16, 0, 0);
}

// ---------------------------------------------------------------------------
// prep: transpose+cast w1, w2 -> [N][K] bf16.  2048 blocks of 256.
__device__ __forceinline__ void transpose_tile(
    const float* __restrict__ in, bf16* __restrict__ out,
    int K, int N, int bx, int by, int t, bf16 (*tile)[72])
{
    const int k0 = by * 64;
    const int n0 = bx * 64;
    const int lr = t >> 4;          // 0..15
    const int lc = (t & 15) << 2;   // 0,4,..60
#pragma unroll
    for (int p = 0; p < 4; ++p) {
        int k = p * 16 + lr;
        float4 v = *(const float4*)(in + (size_t)(k0 + k) * N + n0 + lc);
        tile[lc + 0][k] = (bf16)v.x;
        tile[lc + 1][k] = (bf16)v.y;
        tile[lc + 2][k] = (bf16)v.z;
        tile[lc + 3][k] = (bf16)v.w;
    }
    __syncthreads();
    const int wr = t >> 3;          // 0..31
    const int wc = (t & 7) << 3;    // 0,8,..56
#pragma unroll
    for (int p = 0; p < 2; ++p) {
        int n = p * 32 + wr;
        *(bf16x8*)(out + (size_t)(n0 + n) * K + k0 + wc) =
            *(const bf16x8*)&tile[n][wc];
    }
}

__global__ __launch_bounds__(256) void prep(
    const float* __restrict__ w1, bf16* __restrict__ w1t,
    const float* __restrict__ w2, bf16* __restrict__ w2t)
{
    __shared__ __align__(16) bf16 tile[64][72];
    const int b = blockIdx.x;
    const int t = threadIdx.x;
    if (b < 1024) {                      // w1 [1024][4096] -> w1t [4096][1024]
        transpose_tile(w1, w1t, 1024, 4096, b & 63, b >> 6, t, tile);
    } else {                             // w2 [4096][1024] -> w2t [1024][4096]
        int b2 = b - 1024;
        transpose_tile(w2, w2t, 4096, 1024, b2 & 15, b2 >> 4, t, tile);
    }
}

// ---------------------------------------------------------------------------
// C[m][n] = sum_k A[m][k] * Bt[n][k]  (+bias, opt relu)
// Bt [N][K] bf16.  A is f32 [M][K] when A_F32 (GEMM1, in-kernel cast) else
// bf16 [M][K] (GEMM2 = exact R2 kernel).  Block = 256 thr = 4 waves, tile
// 128x128, BK=64, single LDS buffer, 2 barriers/iter.  16x16x32 bf16 MFMA.
// LDS rule: slot s of row r holds global chunk s^(r&7); frag reads use
// ch = ((h*4+quad)^r7)*16B  (0 bank conflicts, measured R2/R5).
template <int FUSE_RELU_BF16, int A_F32>
__global__ __launch_bounds__(256, 3) void gemm_bt(
    const void* __restrict__ Ain, const bf16* __restrict__ Bt,
    const float* __restrict__ bias, void* __restrict__ Cout,
    int M, int N, int K)
{
    __shared__ __align__(16) bf16 As[BM * BK];   // 16 KiB
    __shared__ __align__(16) bf16 Bs[BN * BK];   // 16 KiB

    const int bx = blockIdx.x;
    const int by = blockIdx.y;

    const int tid  = threadIdx.x;
    const int wave = tid >> 6;
    const int lane = tid & 63;

    const int l8  = lane >> 3;           // row within 8-row group
    const int c8  = lane & 7;            // 16B-chunk index
    const int swc = (c8 ^ l8) << 3;      // swizzled global chunk (bf16 elems)
    const size_t K_ = (size_t)K;

    // ---- B staging: wave w rows [w*32, w*32+32), 4 DMAs, global-side swizzle
    const bf16* gB[4];
#pragma unroll
    for (int g = 0; g < 4; ++g)
        gB[g] = Bt + ((size_t)bx * BN + wave * 32 + g * 8 + l8) * K_ + swc;
    bf16* lB0 = &Bs[(wave * 32) * BK] + lane * 8;

    // ---- A staging
    // A_F32: lane loads global f32 chunk c8 (two float4), writes LDS slot
    // c8^l8 (content = global chunk c8 = slot^(row&7): rule holds).
    const float* pA32;
    const bf16*  gA[4];
    int wofsA = 0;
    if (A_F32) {
        pA32 = (const float*)Ain +
               ((size_t)by * BM + wave * 32 + l8) * K_ + c8 * 8;
        wofsA = (wave * 32 + l8) * BK + ((c8 ^ l8) << 3);
    } else {
#pragma unroll
        for (int g = 0; g < 4; ++g)
            gA[g] = (const bf16*)Ain +
                    ((size_t)by * BM + wave * 32 + g * 8 + l8) * K_ + swc;
    }
    bf16* lA0 = &As[(wave * 32) * BK] + lane * 8;

    const int wm   = (wave >> 1) << 6;
    const int wn   = (wave & 1) << 6;
    const int quad = lane >> 4;
    const int r    = lane & 15;
    const int r7   = lane & 7;

    f32x4 acc[4][4] = {};
    float4 rlo[4], rhi[4];               // A_F32 prefetch regs (32 VGPR)

    auto gloadA32 = [&]() {
#pragma unroll
        for (int g = 0; g < 4; ++g) {
            const float* p = pA32 + (size_t)(g * 8) * K_;
            rlo[g] = *(const float4*)(p);
            rhi[g] = *(const float4*)(p + 4);
        }
        pA32 += BK;
    };
    auto writeA32 = [&]() {
#pragma unroll
        for (int g = 0; g < 4; ++g) {
            bf16x8 o;
            o[0] = (bf16)rlo[g].x; o[1] = (bf16)rlo[g].y;
            o[2] = (bf16)rlo[g].z; o[3] = (bf16)rlo[g].w;
            o[4] = (bf16)rhi[g].x; o[5] = (bf16)rhi[g].y;
            o[6] = (bf16)rhi[g].z; o[7] = (bf16)rhi[g].w;
            *(bf16x8*)&As[wofsA + g * (8 * BK)] = o;
        }
    };

    const int T = K / BK;
    if (A_F32) gloadA32();               // tile 0 A -> regs

    for (int t = 0; t < T; ++t) {
        __syncthreads();                 // LDS free (prev compute done)
        if (A_F32) {
            writeA32();                  // cvt + swizzled b128 LDS writes
        } else {
#pragma unroll
            for (int g = 0; g < 4; ++g) {
                gload_lds16(gA[g], lA0 + g * (8 * BK));
                gA[g] += BK;
            }
        }
#pragma unroll
        for (int g = 0; g < 4; ++g) {
            gload_lds16(gB[g], lB0 + g * (8 * BK));
            gB[g] += BK;
        }
        __syncthreads();                 // tile t resident
        if (A_F32 && t + 1 < T) gloadA32();  // ages during compute

#pragma unroll
        for (int h = 0; h < 2; ++h) {
            const int ch = ((h * 4 + quad) ^ r7) << 3;
            bf16x8 af[4], bfr[4];
#pragma unroll
            for (int i = 0; i < 4; ++i)
                af[i] = *(const bf16x8*)&As[(wm + i * 16 + r) * BK + ch];
#pragma unroll
            for (int jj = 0; jj < 4; ++jj)
                bfr[jj] = *(const bf16x8*)&Bs[(wn + jj * 16 + r) * BK + ch];
#pragma unroll
            for (int i = 0; i < 4; ++i)
#pragma unroll
                for (int jj = 0; jj < 4; ++jj)
                    acc[i][jj] = __builtin_amdgcn_mfma_f32_16x16x32_bf16(
                        af[i], bfr[jj], acc[i][jj], 0, 0, 0);
        }
    }

    // epilogue: C/D layout col = lane&15, row = quad*4 + reg
    const int m_base = by * BM + wm + quad * 4;
    const int n_base = bx * BN + wn + r;
    float bv[4];
#pragma unroll
    for (int jj = 0; jj < 4; ++jj) bv[jj] = bias[n_base + jj * 16];

    if (FUSE_RELU_BF16) {
        bf16* Cb = (bf16*)Cout;
#pragma unroll
        for (int i = 0; i < 4; ++i) {
#pragma unroll
            for (int p = 0; p < 4; ++p) {
                size_t row = (size_t)(m_base + i * 16 + p) * (size_t)N;
#pragma unroll
                for (int jj = 0; jj < 4; ++jj) {
                    float v = acc[i][jj][p] + bv[jj];
                    v = v > 0.f ? v : 0.f;
                    Cb[row + n_base + jj * 16] = (bf16)v;
                }
            }
        }
    } else {
        float* Cf = (float*)Cout;
#pragma unroll
        for (int i = 0; i < 4; ++i) {
#pragma unroll
            for (int p = 0; p < 4; ++p) {
                size_t row = (size_t)(m_base + i * 16 + p) * (size_t)N;
#pragma unroll
                for (int jj = 0; jj < 4; ++jj) {
                    Cf[row + n_base + jj * 16] = acc[i][jj][p] + bv[jj];
                }
            }
        }
    }
}

// ---------------------------------------------------------------------------
extern "C" void kernel_launch(void* const* d_in, const int* in_sizes, int n_in,
                              void* d_out, int out_size, void* d_ws, size_t ws_size,
                              hipStream_t stream)
{
    const float* x  = (const float*)d_in[0];  // [8192,1024]
    const float* w1 = (const float*)d_in[1];  // [1024,4096]
    const float* b1 = (const float*)d_in[2];  // [4096]
    const float* w2 = (const float*)d_in[3];  // [4096,1024]
    const float* b2 = (const float*)d_in[4];  // [1024]
    float* out = (float*)d_out;               // [8192,1024]

    const int M = 8192, D = 1024, W = 4096;

    char* ws = (char*)d_ws;
    bf16* h   = (bf16*)(ws);                           // 64 MiB: [8192,4096]
    bf16* w1t = (bf16*)(ws + (size_t)(64 << 20));      //  8 MiB: [4096,1024]
    bf16* w2t = (bf16*)(ws + (size_t)(72 << 20));      //  8 MiB: [1024,4096]

    // 1. prep: weight transposes only (2048 blocks)
    prep<<<1024 + 1024, 256, 0, stream>>>(w1, w1t, w2, w2t);

    // 2. h = relu(x @ w1 + b1), bf16  [M][W]  -- A staged from f32 in-kernel
    gemm_bt<1, 1><<<dim3(W / BN, M / BM), 256, 0, stream>>>(
        (const void*)x, w1t, b1, (void*)h, M, W, D);

    // 3. out = h @ w2 + b2, f32  [M][D]       -- exact R2 kernel
    gemm_bt<0, 0><<<dim3(D / BN, M / BM), 256, 0, stream>>>(
        (const void*)h, w2t, b2, (void*)out, M, D, W);
}